// Round 17
// baseline (788.842 us; speedup 1.0000x reference)
//
#include <hip/hip_runtime.h>
#include <stdint.h>

// E=8, C=1024, H=2048, I=4096.  gate_up = X@Wgu; act = silu(g)*u; out = act@Wd
// Round 17: TLP attack. R13/R16 ran 8 waves x (128 VGPR + 128 AGPR acc) =
// 2048 regs = the full CU register pool -> 2 waves/SIMD, latency-bound
// (LDS BW only ~19% used). This round: 1024-thread blocks, 4x4 wave grid,
// wave output 64x64 (acc=64 regs) -> ~125 regs/wave -> 16 waves/CU =
// 4 waves/SIMD. Same 256x256 tile, BK=64, counted-vmcnt ledger (A=2 gload,
// B=8 dwordx2/thread), fused B transpose+cvt, silu in epilogue.
// Swizzle f(q)=(q^(q>>1)^(q>>2))&7: conflict-free for 16-consecutive-row
// frag reads (2x/slot), stride-2 B ds_writes (8 slots), A gload rows.

#define E_  8
#define C_  1024
#define H_  2048
#define I_  4096
#define N1_ 8192   // 2*I

typedef __bf16 bf16x8 __attribute__((ext_vector_type(8)));
typedef float  f32x4  __attribute__((ext_vector_type(4)));

typedef __attribute__((address_space(3))) unsigned       lds_uint;
typedef const __attribute__((address_space(1))) unsigned glob_uint;

__device__ __forceinline__ void gload_lds16(const void* g, void* l) {
    __builtin_amdgcn_global_load_lds((glob_uint*)g, (lds_uint*)l, 16, 0, 0);
}

__device__ __forceinline__ unsigned short f2bf(float f) {
    union { float f; unsigned u; } v; v.f = f;
    unsigned u = v.u;
    return (unsigned short)((u + 0x7FFFu + ((u >> 16) & 1u)) >> 16);  // RNE
}

__device__ __forceinline__ unsigned swzf(unsigned q) {
    return ((q ^ (q >> 1) ^ (q >> 2)) & 7u) << 4;   // 16B-slot XOR constant
}

#define SBAR0 __builtin_amdgcn_sched_barrier(0)
#define MFMA_ __builtin_amdgcn_mfma_f32_16x16x32_bf16

// ---------------- elementwise fp32 -> bf16 (X only) ----------------
__global__ void k_convert(const float* __restrict__ src,
                          unsigned short* __restrict__ dst, int n8) {
    int idx = blockIdx.x * blockDim.x + threadIdx.x;
    int stride = gridDim.x * blockDim.x;
    for (int i = idx; i < n8; i += stride) {
        const float4* s = reinterpret_cast<const float4*>(src + (size_t)i * 8);
        float4 a = s[0], b = s[1];
        ushort4 lo, hi;
        lo.x = f2bf(a.x); lo.y = f2bf(a.y); lo.z = f2bf(a.z); lo.w = f2bf(a.w);
        hi.x = f2bf(b.x); hi.y = f2bf(b.y); hi.z = f2bf(b.z); hi.w = f2bf(b.w);
        ushort4* d = reinterpret_cast<ushort4*>(dst + (size_t)i * 8);
        d[0] = lo; d[1] = hi;
    }
}

// ---------------- staging helpers ----------------
// A piece j (16 KiB, rows 128j..128j+127 of [256 rows][128B] swizzled tile)
template<int LD>
__device__ __forceinline__ void stageA(const char* __restrict__ gtile,
                                       char* ldst, int j, int tid, int wave) {
    unsigned p   = (unsigned)(j * 16384 + tid * 16);
    unsigned row = p >> 7;
    unsigned kb  = (p & 127u) ^ swzf(row);
    const char* gp = gtile + (size_t)row * LD + kb;
    void* lp = ldst + j * 16384 + wave * 1024;   // wave-uniform base
    gload_lds16(gp, lp);
}

__device__ __forceinline__ const bf16x8* frag128(const char* tile, int row, int kb) {
    unsigned phys = (unsigned)(row * 128) + ((unsigned)kb ^ swzf((unsigned)row));
    return reinterpret_cast<const bf16x8*>(tile + phys);
}

// B: 8 k-strided dwordx2 (col-pair x 8 k-rows). LDB in elements.
template<int LDB>
__device__ __forceinline__ void loadB8(const float* __restrict__ gcol, int kt,
                                       float2 (&bk)[8]) {
    const float* p = gcol + (size_t)(kt * 64) * LDB;
    #pragma unroll
    for (int i = 0; i < 8; ++i)
        bk[i] = *reinterpret_cast<const float2*>(p + (size_t)i * LDB);
}

// cvt 16 f32 (2 cols x 8 k) -> 2x ds_write_b128 at rows q=2rg+cc, slot ko.
__device__ __forceinline__ void cvtWriteB(char* bB, const float2 (&bk)[8],
                                          int rg, int ko) {
    #pragma unroll
    for (int cc = 0; cc < 2; ++cc) {
        unsigned u[4];
        #pragma unroll
        for (int p2 = 0; p2 < 4; ++p2) {
            float lo = cc ? bk[2 * p2].y     : bk[2 * p2].x;
            float hi = cc ? bk[2 * p2 + 1].y : bk[2 * p2 + 1].x;
            asm("v_cvt_pk_bf16_f32 %0, %1, %2" : "=v"(u[p2]) : "v"(lo), "v"(hi));
        }
        unsigned q = (unsigned)(2 * rg + cc);
        unsigned phys = q * 128 + (((unsigned)ko * 16) ^ swzf(q));
        *reinterpret_cast<uint4*>(bB + phys) = make_uint4(u[0], u[1], u[2], u[3]);
    }
}

// MODE 0: gemm1 (B=Wgu native [H][2I], gate|up 16-col interleave, silu -> bf16)
// MODE 1: gemm2 (B=Wd native [I][H], f32 out)
template<int LDA, int LDB, int NT, int BMG, int BNG, int MODE>
__global__ __launch_bounds__(1024, 4) void k_gemm_f(
    const unsigned short* __restrict__ A,
    const float* __restrict__ B,
    void* __restrict__ Cout,
    size_t sA, size_t sB) {
    __shared__ char lds[131072];   // 2 bufs x (A 32K | B 32K)

    const int tid = threadIdx.x, lane = tid & 63, wave = tid >> 6;
    const int wm = wave >> 2, wn = wave & 3;        // 4x4 wave grid
    const int kg = lane >> 4, r = lane & 15;
    const int rg = tid & 127, ko = tid >> 7;        // B-staging role

    // flattened grid, bijective XCD chunking (gridDim.x % 8 == 0), bm innermost
    unsigned flat = blockIdx.x;
    unsigned cpx = gridDim.x >> 3;
    unsigned nid = (flat & 7u) * cpx + (flat >> 3);
    const int bm = nid % BMG;
    const int bn = (nid / BMG) % BNG;
    const int e  = nid / (BMG * BNG);

    const char* gA = (const char*)(A + sA * e) + (size_t)(bm * 256) * LDA;
    // LDS B-row q=2rg+cc -> global col (MODE 0: q=32a+16b+c -> col 16a+c (+I if b))
    size_t colstart;
    if constexpr (MODE == 0)
        colstart = (size_t)(bn * 128 + ((rg >> 4) * 16) + 2 * (rg & 7))
                 + (((rg >> 3) & 1) ? (size_t)I_ : (size_t)0);
    else
        colstart = (size_t)(bn * 256 + 2 * rg);
    const float* gBcol = B + sB * e + colstart + (size_t)ko * 8 * LDB;

    float2 bk[8];

    // ---------------- prologue ----------------
    loadB8<LDB>(gBcol, 0, bk);
    SBAR0;
    asm volatile("s_waitcnt vmcnt(0)" ::: "memory");
    SBAR0;
    cvtWriteB(lds + 32768, bk, rg, ko);
    SBAR0;
    stageA<LDA>(gA, lds, 0, tid, wave);
    stageA<LDA>(gA, lds, 1, tid, wave);
    SBAR0;
    loadB8<LDB>(gBcol, 1, bk);
    SBAR0;
    asm volatile("s_waitcnt vmcnt(8)" ::: "memory");   // A(0) done; B(1) in flight
    asm volatile("s_waitcnt lgkmcnt(0)" ::: "memory");
    SBAR0;
    __builtin_amdgcn_s_barrier();
    SBAR0;

    f32x4 acc[4][4] = {};

    for (int t = 0; t < NT; ++t) {
        const char* Ab = lds + (t & 1) * 65536;
        const char* Bb = Ab + 32768;
        char* nA = lds + ((t + 1) & 1) * 65536;
        char* nB = nA + 32768;
        const char* gAn = gA + (size_t)(t + 1) * 128;
        const bool hs1 = (t + 1) < NT, hs2 = (t + 2) < NT;

        // ---- tile-top staging (ledger: B8(t+1) regs oldest -> drain) ----
        if (hs1) {
            asm volatile("s_waitcnt vmcnt(0)" ::: "memory");
            SBAR0;
            cvtWriteB(nB, bk, rg, ko);
            SBAR0;
            stageA<LDA>(gAn, nA, 0, tid, wave);
            stageA<LDA>(gAn, nA, 1, tid, wave);
            SBAR0;
            if (hs2) { loadB8<LDB>(gBcol, t + 2, bk); SBAR0; }
        }

        // ---- compute: 2 kk phases, 16 MFMA each (compiler-scheduled) ----
        #pragma unroll
        for (int kk = 0; kk < 2; ++kk) {
            bf16x8 af[4], bf[4];
            #pragma unroll
            for (int m = 0; m < 4; ++m)
                af[m] = *frag128(Ab, wm * 64 + m * 16 + r, kk * 64 + kg * 16);
            #pragma unroll
            for (int n = 0; n < 4; ++n)
                bf[n] = *frag128(Bb, wn * 64 + n * 16 + r, kk * 64 + kg * 16);
            __builtin_amdgcn_s_setprio(1);
            #pragma unroll
            for (int m = 0; m < 4; ++m)
                #pragma unroll
                for (int n = 0; n < 4; ++n)
                    acc[m][n] = MFMA_(af[m], bf[n], acc[m][n], 0, 0, 0);
            __builtin_amdgcn_s_setprio(0);
        }

        // ---- boundary: counted drain (A(t+1) done, B(t+2) in flight) ----
        if (hs1) {
            SBAR0;
            if (hs2) asm volatile("s_waitcnt vmcnt(8)" ::: "memory");
            else     asm volatile("s_waitcnt vmcnt(0)" ::: "memory");
            asm volatile("s_waitcnt lgkmcnt(0)" ::: "memory");
            SBAR0;
            __builtin_amdgcn_s_barrier();
            SBAR0;
        }
    }

    // ---------------- epilogue ----------------
    const int row0 = bm * 256 + wm * 64 + kg * 4;   // + m*16 + j
    if constexpr (MODE == 0) {
        // pairs: (acc[m][0],acc[m][1]) -> col wn*32+r; (acc[m][2],acc[m][3]) -> +16
        unsigned short* act = (unsigned short*)Cout + (size_t)e * C_ * I_;
        const int col0 = bn * 128 + wn * 32 + r;
        #pragma unroll
        for (int m = 0; m < 4; ++m)
            #pragma unroll
            for (int p = 0; p < 2; ++p)
                #pragma unroll
                for (int j = 0; j < 4; ++j) {
                    float g = acc[m][2 * p][j], u = acc[m][2 * p + 1][j];
                    float s = g / (1.0f + __expf(-g)) * u;
                    act[(size_t)(row0 + m * 16 + j) * I_ + col0 + p * 16] = f2bf(s);
                }
    } else {
        float* o = (float*)Cout + (size_t)e * C_ * H_;
        const int col0 = bn * 256 + wn * 64 + r;
        #pragma unroll
        for (int m = 0; m < 4; ++m)
            #pragma unroll
            for (int n = 0; n < 4; ++n)
                #pragma unroll
                for (int j = 0; j < 4; ++j)
                    o[(size_t)(row0 + m * 16 + j) * H_ + col0 + n * 16] = acc[m][n][j];
    }
}

// ---------------- launch ----------------
extern "C" void kernel_launch(void* const* d_in, const int* in_sizes, int n_in,
                              void* d_out, int out_size, void* d_ws, size_t ws_size,
                              hipStream_t stream) {
    const float* hs  = (const float*)d_in[0];   // [E][C][H]
    const float* wgu = (const float*)d_in[1];   // [E][H][2I]
    const float* wd  = (const float*)d_in[2];   // [E][I][H]
    float* out = (float*)d_out;

    char* ws = (char*)d_ws;
    unsigned short* Xbf  = (unsigned short*)(ws);                 // 33,554,432 B
    unsigned short* actb = (unsigned short*)(ws + 33554432ull);   // 67,108,864 B

    k_convert<<<2048, 256, 0, stream>>>(hs, Xbf, E_ * C_ * H_ / 8);

    // GEMM1 (fused transpose+silu): X[EC][H] x Wgu native -> act bf16 [EC][I]
    // BM=256 (BMG=4), 128 act cols/block (BNG=32), NT=32 (BK=64). 1024 blocks.
    k_gemm_f<H_ * 2, N1_, H_ / 64, 4, 32, 0><<<dim3(1024), 1024, 0, stream>>>(
        Xbf, wgu, actb, (size_t)C_ * H_, (size_t)H_ * N1_);

    // GEMM2 (fused transpose): act[EC][I] x Wd native -> out f32 [EC][H]
    // BM=256 (BMG=4), BN=256 (BNG=8), NT=64 (BK=64). 256 blocks.
    k_gemm_f<I_ * 2, H_, I_ / 64, 4, 8, 1><<<dim3(256), 1024, 0, stream>>>(
        actb, wd, out, (size_t)C_ * I_, (size_t)I_ * H_);
}

// Round 18
// 470.925 us; speedup vs baseline: 1.6751x; 1.6751x over previous
//
#include <hip/hip_runtime.h>
#include <stdint.h>

// E=8, C=1024, H=2048, I=4096.  gate_up = X@Wgu; act = silu(g)*u; out = act@Wd
// Round 18 = R16 restored (session best: 470.7 us).
// Final structure:
//  - k_convert: X f32 -> bf16 once (makes per-expert X 4 MB = XCD-L2-resident).
//  - Both GEMMs: 256x256 tile, BK=64, 8 waves (2x4, wave output 128x64),
//    16x16x32 bf16 MFMA, acc[8][4] in AGPRs, __launch_bounds__(512,2).
//  - A: bf16 global_load_lds (width 16) into [256 rows][128B] LDS,
//    XOR swizzle swz8(row)=((row^(row>>2))&7)<<4 applied identically at the
//    pre-swizzled global source and frag reads (involution; 0 bank conflicts).
//  - B: fused transpose+convert from native f32 [K][N] weights: 8 k-strided
//    dwordx4/thread, v_cvt_pk_bf16_f32, 4x ds_write_b128 into the same
//    swizzled layout. Reg prefetch depth 2 tiles; weights cross HBM once.
//  - Tile-top staging block: vmcnt(0) [B(t+1) regs, 1 tile old -> ~free],
//    cvtWriteB, stageA x4, loadB8(t+2). Compute: 4 phases, compiler-scheduled
//    (counted lgkmcnt), setprio(1) around MFMA clusters.
//  - Boundary (FIFO ledger): vmcnt(8) completes exactly A(t+1), leaves
//    B(t+2) in flight; lgkm0; s_barrier.
//  - gemm1 epilogue: silu(g)*u from paired acc cols (gate|up 16-col
//    interleave in the B column map) -> act bf16. gemm2: f32 out.
//  - Flattened grid + bijective XCD chunking (one expert per XCD, bm
//    innermost so 4 consecutive blocks share each B panel via L2).

#define E_  8
#define C_  1024
#define H_  2048
#define I_  4096
#define N1_ 8192   // 2*I

typedef __bf16 bf16x8 __attribute__((ext_vector_type(8)));
typedef float  f32x4  __attribute__((ext_vector_type(4)));

typedef __attribute__((address_space(3))) unsigned       lds_uint;
typedef const __attribute__((address_space(1))) unsigned glob_uint;

__device__ __forceinline__ void gload_lds16(const void* g, void* l) {
    __builtin_amdgcn_global_load_lds((glob_uint*)g, (lds_uint*)l, 16, 0, 0);
}

__device__ __forceinline__ unsigned short f2bf(float f) {
    union { float f; unsigned u; } v; v.f = f;
    unsigned u = v.u;
    return (unsigned short)((u + 0x7FFFu + ((u >> 16) & 1u)) >> 16);  // RNE
}

__device__ __forceinline__ unsigned swz8(unsigned row) {
    return ((row ^ (row >> 2)) & 7u) << 4;   // 16B-slot XOR constant
}

#define SBAR0 __builtin_amdgcn_sched_barrier(0)
#define MFMA_ __builtin_amdgcn_mfma_f32_16x16x32_bf16

// ---------------- elementwise fp32 -> bf16 (X only) ----------------
__global__ void k_convert(const float* __restrict__ src,
                          unsigned short* __restrict__ dst, int n8) {
    int idx = blockIdx.x * blockDim.x + threadIdx.x;
    int stride = gridDim.x * blockDim.x;
    for (int i = idx; i < n8; i += stride) {
        const float4* s = reinterpret_cast<const float4*>(src + (size_t)i * 8);
        float4 a = s[0], b = s[1];
        ushort4 lo, hi;
        lo.x = f2bf(a.x); lo.y = f2bf(a.y); lo.z = f2bf(a.z); lo.w = f2bf(a.w);
        hi.x = f2bf(b.x); hi.y = f2bf(b.y); hi.z = f2bf(b.z); hi.w = f2bf(b.w);
        ushort4* d = reinterpret_cast<ushort4*>(dst + (size_t)i * 8);
        d[0] = lo; d[1] = hi;
    }
}

// ---------------- staging helpers ----------------
template<int LD>
__device__ __forceinline__ void stageA(const char* __restrict__ gtile,
                                       char* ldst, int j, int tid, int wave) {
    unsigned p   = (unsigned)(j * 8192 + tid * 16);
    unsigned row = p >> 7;
    unsigned kb  = (p & 127u) ^ swz8(row);
    const char* gp = gtile + (size_t)row * LD + kb;
    void* lp = ldst + j * 8192 + wave * 1024;   // wave-uniform base
    gload_lds16(gp, lp);
}

__device__ __forceinline__ const bf16x8* frag128(const char* tile, int row, int kb) {
    unsigned phys = (unsigned)(row * 128) + ((unsigned)kb ^ swz8((unsigned)row));
    return reinterpret_cast<const bf16x8*>(tile + phys);
}

template<int LDB>
__device__ __forceinline__ void loadB8(const char* __restrict__ gcol, int kt,
                                       float4 (&bk)[8]) {
    const char* p = gcol + (size_t)(kt * 64) * LDB;
    #pragma unroll
    for (int i = 0; i < 8; ++i)
        bk[i] = *reinterpret_cast<const float4*>(p + (size_t)i * LDB);
}

__device__ __forceinline__ void cvtWriteB(char* bB, const float4 (&bk)[8],
                                          int rg, int kg8) {
    const float* f = reinterpret_cast<const float*>(&bk[0]);
    #pragma unroll
    for (int j = 0; j < 4; ++j) {
        unsigned u[4];
        #pragma unroll
        for (int p2 = 0; p2 < 4; ++p2) {
            float lo = f[(2 * p2) * 4 + j];
            float hi = f[(2 * p2 + 1) * 4 + j];
            asm("v_cvt_pk_bf16_f32 %0, %1, %2" : "=v"(u[p2]) : "v"(lo), "v"(hi));
        }
        unsigned q = (unsigned)(rg * 4 + j);
        unsigned phys = q * 128 + (((unsigned)kg8 * 16) ^ swz8(q));
        *reinterpret_cast<uint4*>(bB + phys) = make_uint4(u[0], u[1], u[2], u[3]);
    }
}

// MODE 0: gemm1 (B=Wgu native [H][2I], gate|up 16-col interleave, silu -> bf16)
// MODE 1: gemm2 (B=Wd native [I][H], f32 out)
template<int LDA, int LDB, int NT, int BMG, int BNG, int MODE>
__global__ __launch_bounds__(512, 2) void k_gemm_f(
    const unsigned short* __restrict__ A,
    const float* __restrict__ B,
    void* __restrict__ Cout,
    size_t sA, size_t sB) {
    __shared__ char lds[131072];   // 2 bufs x (A 32K | B 32K)

    const int tid = threadIdx.x, lane = tid & 63, wave = tid >> 6;
    const int wm = wave >> 2, wn = wave & 3;
    const int kg = lane >> 4, r = lane & 15;
    const int rg = tid & 255, kg8 = tid >> 8;   // B-staging role
    const int rgl = tid & 63;                   // (compat: rg in [0,64) layout)

    // flattened grid, bijective XCD chunking (gridDim.x % 8 == 0), bm innermost
    unsigned flat = blockIdx.x;
    unsigned cpx = gridDim.x >> 3;
    unsigned nid = (flat & 7u) * cpx + (flat >> 3);
    const int bm = nid % BMG;
    const int bn = (nid / BMG) % BNG;
    const int e  = nid / (BMG * BNG);

    const char* gA = (const char*)(A + sA * e) + (size_t)(bm * 256) * LDA;
    size_t colstart;
    if constexpr (MODE == 0)
        colstart = (size_t)(bn * 128 + ((rgl >> 4) & 3) * 32 + ((rgl >> 2) & 1) * 16
                            + (rgl & 3) * 4)
                 + (((rgl >> 3) & 1) ? (size_t)I_ : (size_t)0);
    else
        colstart = (size_t)(bn * 256 + rgl * 4);
    const char* gBcol = (const char*)B + sB * e + colstart * 4
                      + (size_t)(tid >> 6) * 8 * LDB;

    float4 bk[8];

    // ---------------- prologue ----------------
    loadB8<LDB>(gBcol, 0, bk);
    SBAR0;
    asm volatile("s_waitcnt vmcnt(0)" ::: "memory");
    SBAR0;
    cvtWriteB(lds + 32768, bk, rgl, tid >> 6);
    SBAR0;
    stageA<LDA>(gA, lds, 0, tid, wave);
    stageA<LDA>(gA, lds, 1, tid, wave);
    stageA<LDA>(gA, lds, 2, tid, wave);
    stageA<LDA>(gA, lds, 3, tid, wave);
    SBAR0;
    loadB8<LDB>(gBcol, 1, bk);
    SBAR0;
    asm volatile("s_waitcnt vmcnt(8)" ::: "memory");   // A(0) done; B(1) in flight
    asm volatile("s_waitcnt lgkmcnt(0)" ::: "memory");
    SBAR0;
    __builtin_amdgcn_s_barrier();
    SBAR0;

    f32x4 acc[8][4] = {};

    for (int t = 0; t < NT; ++t) {
        const char* Ab = lds + (t & 1) * 65536;
        const char* Bb = Ab + 32768;
        char* nA = lds + ((t + 1) & 1) * 65536;
        char* nB = nA + 32768;
        const char* gAn = gA + (size_t)(t + 1) * 128;
        const bool hs1 = (t + 1) < NT, hs2 = (t + 2) < NT;

        bf16x8 af[8], b0[2], bg[2];

        // ---- tile-top staging block (off the MFMA critical path) ----
        if (hs1) {
            asm volatile("s_waitcnt vmcnt(0)" ::: "memory");   // bk = B(t+1) f32 done
            SBAR0;
            cvtWriteB(nB, bk, rgl, tid >> 6);
            SBAR0;
            stageA<LDA>(gAn, nA, 0, tid, wave);
            stageA<LDA>(gAn, nA, 1, tid, wave);
            stageA<LDA>(gAn, nA, 2, tid, wave);
            stageA<LDA>(gAn, nA, 3, tid, wave);
            SBAR0;
            if (hs2) { loadB8<LDB>(gBcol, t + 2, bk); SBAR0; }
        }

        // ---- compute phases: compiler-scheduled (counted lgkmcnt) ----
        // phase 0: kk0, n0-1
        #pragma unroll
        for (int m = 0; m < 8; ++m)
            af[m] = *frag128(Ab, wm * 128 + m * 16 + r, kg * 16);
        #pragma unroll
        for (int n = 0; n < 2; ++n)
            b0[n] = *frag128(Bb, wn * 64 + n * 16 + r, kg * 16);
        __builtin_amdgcn_s_setprio(1);
        #pragma unroll
        for (int m = 0; m < 8; ++m) {
            acc[m][0] = MFMA_(af[m], b0[0], acc[m][0], 0, 0, 0);
            acc[m][1] = MFMA_(af[m], b0[1], acc[m][1], 0, 0, 0);
        }
        __builtin_amdgcn_s_setprio(0);

        // phase 1: kk0, n2-3
        #pragma unroll
        for (int n = 0; n < 2; ++n)
            bg[n] = *frag128(Bb, wn * 64 + 32 + n * 16 + r, kg * 16);
        __builtin_amdgcn_s_setprio(1);
        #pragma unroll
        for (int m = 0; m < 8; ++m) {
            acc[m][2] = MFMA_(af[m], bg[0], acc[m][2], 0, 0, 0);
            acc[m][3] = MFMA_(af[m], bg[1], acc[m][3], 0, 0, 0);
        }
        __builtin_amdgcn_s_setprio(0);

        // phase 2: kk1, n0-1
        #pragma unroll
        for (int m = 0; m < 8; ++m)
            af[m] = *frag128(Ab, wm * 128 + m * 16 + r, 64 + kg * 16);
        #pragma unroll
        for (int n = 0; n < 2; ++n)
            b0[n] = *frag128(Bb, wn * 64 + n * 16 + r, 64 + kg * 16);
        __builtin_amdgcn_s_setprio(1);
        #pragma unroll
        for (int m = 0; m < 8; ++m) {
            acc[m][0] = MFMA_(af[m], b0[0], acc[m][0], 0, 0, 0);
            acc[m][1] = MFMA_(af[m], b0[1], acc[m][1], 0, 0, 0);
        }
        __builtin_amdgcn_s_setprio(0);

        // phase 3: kk1, n2-3
        #pragma unroll
        for (int n = 0; n < 2; ++n)
            bg[n] = *frag128(Bb, wn * 64 + 32 + n * 16 + r, 64 + kg * 16);
        __builtin_amdgcn_s_setprio(1);
        #pragma unroll
        for (int m = 0; m < 8; ++m) {
            acc[m][2] = MFMA_(af[m], bg[0], acc[m][2], 0, 0, 0);
            acc[m][3] = MFMA_(af[m], bg[1], acc[m][3], 0, 0, 0);
        }
        __builtin_amdgcn_s_setprio(0);

        // ---- boundary: counted drain (A(t+1) done, B(t+2) in flight) ----
        if (hs1) {
            SBAR0;
            if (hs2) asm volatile("s_waitcnt vmcnt(8)" ::: "memory");
            else     asm volatile("s_waitcnt vmcnt(0)" ::: "memory");
            asm volatile("s_waitcnt lgkmcnt(0)" ::: "memory");
            SBAR0;
            __builtin_amdgcn_s_barrier();
            SBAR0;
        }
    }

    // ---------------- epilogue ----------------
    const int row0 = bm * 256 + wm * 128 + kg * 4;   // + m*16 + j
    if constexpr (MODE == 0) {
        unsigned short* act = (unsigned short*)Cout + (size_t)e * C_ * I_;
        const int col0 = bn * 128 + wn * 32 + r;
        #pragma unroll
        for (int m = 0; m < 8; ++m)
            #pragma unroll
            for (int n = 0; n < 2; ++n)
                #pragma unroll
                for (int j = 0; j < 4; ++j) {
                    float g = acc[m][n][j], u = acc[m][n + 2][j];
                    float s = g / (1.0f + __expf(-g)) * u;
                    act[(size_t)(row0 + m * 16 + j) * I_ + col0 + n * 16] = f2bf(s);
                }
    } else {
        float* o = (float*)Cout + (size_t)e * C_ * H_;
        const int col0 = bn * 256 + wn * 64 + r;
        #pragma unroll
        for (int m = 0; m < 8; ++m)
            #pragma unroll
            for (int n = 0; n < 4; ++n)
                #pragma unroll
                for (int j = 0; j < 4; ++j)
                    o[(size_t)(row0 + m * 16 + j) * H_ + col0 + n * 16] = acc[m][n][j];
    }
}

// ---------------- launch ----------------
extern "C" void kernel_launch(void* const* d_in, const int* in_sizes, int n_in,
                              void* d_out, int out_size, void* d_ws, size_t ws_size,
                              hipStream_t stream) {
    const float* hs  = (const float*)d_in[0];   // [E][C][H]
    const float* wgu = (const float*)d_in[1];   // [E][H][2I]
    const float* wd  = (const float*)d_in[2];   // [E][I][H]
    float* out = (float*)d_out;

    char* ws = (char*)d_ws;
    unsigned short* Xbf  = (unsigned short*)(ws);                 // 33,554,432 B
    unsigned short* actb = (unsigned short*)(ws + 33554432ull);   // 67,108,864 B

    k_convert<<<2048, 256, 0, stream>>>(hs, Xbf, E_ * C_ * H_ / 8);

    // GEMM1 (fused transpose+silu): X[EC][H] x Wgu native -> act bf16 [EC][I]
    // BM=256 (BMG=4), 128 act cols/block (BNG=32), NT=32 (BK=64). 1024 blocks.
    k_gemm_f<H_ * 2, N1_ * 4, H_ / 64, 4, 32, 0><<<dim3(1024), 512, 0, stream>>>(
        Xbf, wgu, actb, (size_t)C_ * H_, (size_t)H_ * N1_ * 4);

    // GEMM2 (fused transpose): act[EC][I] x Wd native -> out f32 [EC][H]
    // BM=256 (BMG=4), BN=256 (BNG=8), NT=64 (BK=64). 256 blocks.
    k_gemm_f<I_ * 2, H_ * 4, I_ / 64, 4, 8, 1><<<dim3(256), 512, 0, stream>>>(
        actb, wd, out, (size_t)C_ * I_, (size_t)I_ * H_ * 4);
}